// Round 1
// baseline (513.916 us; speedup 1.0000x reference)
//
#include <hip/hip_runtime.h>
#include <hip/hip_bf16.h>
#include <stdint.h>

// Problem constants (fixed by reference)
#define TSEQ   2048
#define DMODEL 1024
#define NH     16
#define HDIM   64
#define NKVH   4

typedef __attribute__((ext_vector_type(8))) short short8;
typedef __attribute__((ext_vector_type(8))) _Float16 half8;
typedef __attribute__((ext_vector_type(4))) float f32x4;
typedef __hip_bfloat16 bf16;

// priority comparator: higher score wins; tie -> lower index wins (matches jax top_k)
__device__ __forceinline__ bool pgt(float as, int ai, float bs, int bi) {
    return (as > bs) || (as == bs && ai < bi);
}

// full bitonic sort across 64 lanes, ascending by priority (validated R6)
__device__ __forceinline__ void bsort(float& s, int& i, int lane) {
#pragma unroll
    for (int k = 2; k <= 64; k <<= 1) {
#pragma unroll
        for (int j = k >> 1; j > 0; j >>= 1) {
            float os = __shfl_xor(s, j, 64);
            int   oi = __shfl_xor(i, j, 64);
            bool lower = (lane & j) == 0;
            bool asc   = (lane & k) == 0;
            bool wmin  = (lower == asc);
            bool takeo = (pgt(s, i, os, oi) == wmin);
            if (takeo) { s = os; i = oi; }
        }
    }
}

// bitonic -> ascending cleanup (6 stages) (validated R6)
__device__ __forceinline__ void bmerge(float& s, int& i, int lane) {
#pragma unroll
    for (int j = 32; j > 0; j >>= 1) {
        float os = __shfl_xor(s, j, 64);
        int   oi = __shfl_xor(i, j, 64);
        bool lower = (lane & j) == 0;
        bool takeo = (pgt(s, i, os, oi) == lower);
        if (takeo) { s = os; i = oi; }
    }
}

// ---- fp32 -> bf16 conversion of x, wq, wkv, wo ----
__global__ __launch_bounds__(256) void convert_bf16(
    const float* __restrict__ x, const float* __restrict__ wq,
    const float* __restrict__ wkv, const float* __restrict__ wo,
    bf16* __restrict__ cx, bf16* __restrict__ cwq,
    bf16* __restrict__ cwkv, bf16* __restrict__ cwo)
{
    const size_t i0 = (size_t)blockIdx.x * 256 + threadIdx.x;
    const size_t stride = (size_t)gridDim.x * 256;
    for (size_t i = i0; i < 2097152; i += stride) cx[i]   = __float2bfloat16(x[i]);
    for (size_t i = i0; i < 1048576; i += stride) cwq[i]  = __float2bfloat16(wq[i]);
    for (size_t i = i0; i < 524288;  i += stride) cwkv[i] = __float2bfloat16(wkv[i]);
    for (size_t i = i0; i < 1048576; i += stride) cwo[i]  = __float2bfloat16(wo[i]);
}

// ---- MFMA GEMM: C[M,N] fp32 = A[M,K](bf16) @ B[K,N](bf16) + bias[N](fp32)
// 64x64 tile, 4 waves, mfma 16x16x32. (R2 code — validated.)
__global__ __launch_bounds__(256) void gemm_bias(
    const bf16* __restrict__ A, const bf16* __restrict__ B,
    const float* __restrict__ bias, float* __restrict__ C,
    int M, int N, int K)
{
    __shared__ short As[64][32];   // (m, k)
    __shared__ short Bt[64][32];   // (n, k)
    const int tid = threadIdx.x;
    const int m0 = blockIdx.y * 64, n0 = blockIdx.x * 64;
    const int w = tid >> 6, lane = tid & 63;
    const int q = lane >> 4, mm = lane & 15;
    f32x4 acc[4];
#pragma unroll
    for (int nb = 0; nb < 4; ++nb) acc[nb] = (f32x4){0.f, 0.f, 0.f, 0.f};
    const int arow = tid >> 2, akc = (tid & 3) * 8;
    const int brow = tid >> 3, bnc = (tid & 7) * 8;
    const short* Ag = (const short*)A;
    const short* Bg = (const short*)B;
    for (int k0 = 0; k0 < K; k0 += 32) {
        __syncthreads();
        short8 av = *(const short8*)(Ag + (size_t)(m0 + arow) * K + k0 + akc);
        *(short8*)(&As[arow][akc]) = av;
        short8 bv = *(const short8*)(Bg + (size_t)(k0 + brow) * N + n0 + bnc);
#pragma unroll
        for (int jj = 0; jj < 8; ++jj) Bt[bnc + jj][brow] = bv[jj];
        __syncthreads();
        short8 af = *(const short8*)(&As[w * 16 + mm][q * 8]);
#pragma unroll
        for (int nb = 0; nb < 4; ++nb) {
            short8 bfr = *(const short8*)(&Bt[nb * 16 + mm][q * 8]);
            acc[nb] = __builtin_amdgcn_mfma_f32_16x16x32_bf16(af, bfr, acc[nb], 0, 0, 0);
        }
    }
#pragma unroll
    for (int nb = 0; nb < 4; ++nb) {
#pragma unroll
        for (int r = 0; r < 4; ++r) {
            int row = m0 + w * 16 + q * 4 + r;
            int col = n0 + nb * 16 + mm;
            C[(size_t)row * N + col] = acc[nb][r] + bias[col];
        }
    }
}

// ---- RMSNorm q and k; emit f16 Q (scale 1/8 folded), f16 K (kvh,t,d), fp32 V ----
__global__ __launch_bounds__(256) void norm_kernel(
    const float* __restrict__ qbuf, const float* __restrict__ kvbuf,
    const float* __restrict__ qn_w, const float* __restrict__ kn_w,
    _Float16* __restrict__ qh, _Float16* __restrict__ kh, float* __restrict__ vbuf)
{
    const int t = blockIdx.x;
    const int tid = threadIdx.x;
#pragma unroll
    for (int it = 0; it < 6; ++it) {
        int idx = it * 256 + tid;
        int chunk = idx >> 6;        // 0..15 q heads, 16..19 k kvh, 20..23 v kvh
        int d = idx & 63;
        float val;
        if (chunk < 16)      val = qbuf[(size_t)t * DMODEL + chunk * 64 + d];
        else if (chunk < 20) val = kvbuf[(size_t)t * 512 + (chunk - 16) * 64 + d];
        else                 val = kvbuf[(size_t)t * 512 + 256 + (chunk - 20) * 64 + d];
        if (chunk < 20) {
            float ss = val * val;
#pragma unroll
            for (int j = 32; j > 0; j >>= 1) ss += __shfl_xor(ss, j, 64);
            float rs = 1.0f / sqrtf(ss * (1.0f / 64.0f) + 1e-8f);
            if (chunk < 16) {
                qh[(size_t)t * DMODEL + chunk * 64 + d] =
                    (_Float16)(val * rs * qn_w[d] * 0.125f);
            } else {
                kh[((size_t)(chunk - 16) * TSEQ + t) * HDIM + d] =
                    (_Float16)(val * rs * kn_w[d]);
            }
        } else {
            vbuf[((size_t)(chunk - 20) * TSEQ + t) * HDIM + d] = val;
        }
    }
}

// ---- fused MFMA scores + exact top-64 + softmax + V gather ----
// block = (h, 16 queries), 4 waves. Each wave computes 16x64 score tiles via
// mfma_f32_16x16x32_f16 for its round-robin chunk subset (newest-first),
// maintains per-row kept-64 (validated bitonic merge), then a 3-merge bitonic
// tree combines the 4 partial top-64 sets (top-k is associative).
__global__ __launch_bounds__(256, 4) void attn_kernel(
    const _Float16* __restrict__ qh, const _Float16* __restrict__ kh,
    const float* __restrict__ vbuf, bf16* __restrict__ ybuf)
{
    // 32 KB union: phase 1: per-wave S tiles [16][65] at w*1040.
    // phase 2 (after barrier): kept scores [4][16][64] @0, kept idx @ +4096 floats.
    __shared__ float lsbuf[8192];
    const int tid = threadIdx.x;
    const int w = tid >> 6, lane = tid & 63;
    const int mm = lane & 15, q4 = lane >> 4;
    const int h = blockIdx.x & 15;
    const int t0 = (127 - (blockIdx.x >> 4)) << 4;   // heavy blocks first
    const int kvh = h >> 2;
    const float slope = exp2f(-((float)h) * (8.0f / 15.0f));

    // Q fragments (f16, scale folded), A-frag layout: row=lane&15, k=(lane>>4)*8..+7
    const _Float16* qp = qh + (size_t)(t0 + mm) * DMODEL + h * HDIM + q4 * 8;
    half8 qf0 = *(const half8*)(qp);        // d 0..31
    half8 qf1 = *(const half8*)(qp + 32);   // d 32..63

    float cs[16]; int ci[16];
#pragma unroll
    for (int r = 0; r < 16; ++r) { cs[r] = -1e30f; ci[r] = 0; }

    float* Sw = lsbuf + w * 1040;           // [16][65]
    const _Float16* kbase = kh + (size_t)kvh * TSEQ * HDIM;
    const int nch = (t0 + 15) >> 6;

    for (int c = nch - w; c >= 0; c -= 4) {
        const int jb = c << 6;
        // B-frag: n=key=jt*16+mm, k=d=(lane>>4)*8..+7 (same (n,k) pattern as gemm)
        const _Float16* kp = kbase + ((size_t)jb + mm) * HDIM + q4 * 8;
        f32x4 acc[4];
#pragma unroll
        for (int jt = 0; jt < 4; ++jt) {
            half8 b0 = *(const half8*)(kp + jt * 16 * HDIM);
            half8 b1 = *(const half8*)(kp + jt * 16 * HDIM + 32);
            f32x4 a = __builtin_amdgcn_mfma_f32_16x16x32_f16(
                qf0, b0, (f32x4){0.f, 0.f, 0.f, 0.f}, 0, 0, 0);
            acc[jt] = __builtin_amdgcn_mfma_f32_16x16x32_f16(qf1, b1, a, 0, 0, 0);
        }
        // C layout: col=lane&15 (key), row=(lane>>4)*4+reg (query). Transpose via LDS.
#pragma unroll
        for (int jt = 0; jt < 4; ++jt)
#pragma unroll
            for (int rr = 0; rr < 4; ++rr)
                Sw[(q4 * 4 + rr) * 65 + jt * 16 + mm] = acc[jt][rr];
        // same-wave LDS: compiler inserts lgkmcnt before dependent reads
#pragma unroll
        for (int r = 0; r < 16; ++r) {
            float sr = Sw[r * 65 + lane];
            int dist = (t0 + r) - (jb + lane);
            float s = (dist >= 0) ? sr - slope * (float)dist : -1e30f;
            float th = __shfl(cs[r], 0, 64);   // current min of kept (ascending)
            if (__any(s >= th)) {
                float ns = s; int ni = jb + lane;
                bsort(ns, ni, lane);
                float rsv = __shfl_xor(ns, 63, 64);   // descending view
                int   riv = __shfl_xor(ni, 63, 64);
                if (pgt(rsv, riv, cs[r], ci[r])) { cs[r] = rsv; ci[r] = riv; }
                bmerge(cs[r], ci[r], lane);           // restore ascending
            }
        }
    }
    __syncthreads();   // all S-tile use done; safe to reuse LDS for kept sets
    float* ks = lsbuf;
    int*   ki = (int*)(lsbuf + 4096);
#pragma unroll
    for (int r = 0; r < 16; ++r) {
        ks[(w * 16 + r) * 64 + lane] = cs[r];
        ki[(w * 16 + r) * 64 + lane] = ci[r];
    }
    __syncthreads();
    // wave w owns rows w*4..w*4+3: merge the 4 kept sets, softmax, gather
    const float* vb = vbuf + (size_t)kvh * TSEQ * HDIM + lane;
#pragma unroll
    for (int rr = 0; rr < 4; ++rr) {
        int r = w * 4 + rr;
        // top64(slot0 ∪ slot2)
        float as = ks[(0 * 16 + r) * 64 + lane];
        int   ai = ki[(0 * 16 + r) * 64 + lane];
        float bs = ks[(2 * 16 + r) * 64 + (63 - lane)];
        int   bi = ki[(2 * 16 + r) * 64 + (63 - lane)];
        if (pgt(bs, bi, as, ai)) { as = bs; ai = bi; }
        bmerge(as, ai, lane);
        // top64(slot1 ∪ slot3)
        float cs2 = ks[(1 * 16 + r) * 64 + lane];
        int   ci2 = ki[(1 * 16 + r) * 64 + lane];
        float ds2 = ks[(3 * 16 + r) * 64 + (63 - lane)];
        int   di2 = ki[(3 * 16 + r) * 64 + (63 - lane)];
        if (pgt(ds2, di2, cs2, ci2)) { cs2 = ds2; ci2 = di2; }
        bmerge(cs2, ci2, lane);
        // final top64 of union
        float es = __shfl_xor(cs2, 63, 64);
        int   ei = __shfl_xor(ci2, 63, 64);
        if (pgt(es, ei, as, ai)) { as = es; ai = ei; }
        bmerge(as, ai, lane);
        // softmax over kept 64 (pads -1e30 -> weight 0); max at lane 63
        float msx = __shfl(as, 63, 64);
        bool valid = as > -1e29f;
        float p = valid ? __expf(as - msx) : 0.f;
        float l = p;
#pragma unroll
        for (int j2 = 32; j2 > 0; j2 >>= 1) l += __shfl_xor(l, j2, 64);
        float wgt = p / l;
        int widx = valid ? ai : 0;
        float accv = 0.f;
#pragma unroll 8
        for (int i = 0; i < 64; ++i) {
            float wv = __shfl(wgt, i, 64);
            int  ix = __shfl(widx, i, 64);
            accv += wv * vb[(size_t)ix * HDIM];
        }
        ybuf[(size_t)(t0 + r) * DMODEL + h * HDIM + lane] = __float2bfloat16(accv);
    }
}

extern "C" void kernel_launch(void* const* d_in, const int* in_sizes, int n_in,
                              void* d_out, int out_size, void* d_ws, size_t ws_size,
                              hipStream_t stream)
{
    // d_in order: x, wq, bq, wkv, bkv, wo, bo, qn_w, kn_w  (all fp32)
    const float* x    = (const float*)d_in[0];
    const float* wq   = (const float*)d_in[1];
    const float* bq   = (const float*)d_in[2];
    const float* wkv  = (const float*)d_in[3];
    const float* bkv  = (const float*)d_in[4];
    const float* wo   = (const float*)d_in[5];
    const float* bo   = (const float*)d_in[6];
    const float* qn_w = (const float*)d_in[7];
    const float* kn_w = (const float*)d_in[8];
    char* ws = (char*)d_ws;
    // ws layout (28 MB):
    // cx bf16 4M @0 (reused as qh f16 4M after kv-gemm) | cwq 2M @4M | cwkv 1M @6M |
    // cwo 2M @7M | qbuf fp32 8M @9M | kvbuf fp32 4M @17M | kh f16 1M @21M |
    // vbuf fp32 2M @22M | ybuf bf16 4M @24M
    bf16*      cx    = (bf16*)(ws);
    bf16*      cwq   = (bf16*)(ws + ((size_t)4  << 20));
    bf16*      cwkv  = (bf16*)(ws + ((size_t)6  << 20));
    bf16*      cwo   = (bf16*)(ws + ((size_t)7  << 20));
    float*     qbuf  = (float*)(ws + ((size_t)9  << 20));
    float*     kvbuf = (float*)(ws + ((size_t)17 << 20));
    _Float16*  qh    = (_Float16*)(ws);                      // overlays dead cx
    _Float16*  kh    = (_Float16*)(ws + ((size_t)21 << 20));
    float*     vbuf  = (float*)(ws + ((size_t)22 << 20));
    bf16*      ybuf  = (bf16*)(ws + ((size_t)24 << 20));
    float*     out   = (float*)d_out;   // fp32 output

    convert_bf16<<<2048, 256, 0, stream>>>(x, wq, wkv, wo, cx, cwq, cwkv, cwo);
    gemm_bias<<<dim3(DMODEL / 64, TSEQ / 64), 256, 0, stream>>>(
        cx, cwq, bq, qbuf, TSEQ, DMODEL, DMODEL);
    gemm_bias<<<dim3(512 / 64, TSEQ / 64), 256, 0, stream>>>(
        cx, cwkv, bkv, kvbuf, TSEQ, 512, DMODEL);
    norm_kernel<<<TSEQ, 256, 0, stream>>>(qbuf, kvbuf, qn_w, kn_w, qh, kh, vbuf);
    attn_kernel<<<NH * (TSEQ / 16), 256, 0, stream>>>(qh, kh, vbuf, ybuf);
    gemm_bias<<<dim3(DMODEL / 64, TSEQ / 64), 256, 0, stream>>>(
        ybuf, cwo, bo, out, TSEQ, DMODEL, DMODEL);
}

// Round 2
// 394.078 us; speedup vs baseline: 1.3041x; 1.3041x over previous
//
#include <hip/hip_runtime.h>
#include <hip/hip_bf16.h>
#include <stdint.h>

// Problem constants (fixed by reference)
#define TSEQ   2048
#define DMODEL 1024
#define NH     16
#define HDIM   64
#define NKVH   4

typedef __attribute__((ext_vector_type(8))) short short8;
typedef __attribute__((ext_vector_type(8))) _Float16 half8;
typedef __attribute__((ext_vector_type(4))) float f32x4;
typedef __hip_bfloat16 bf16;

// priority comparator: higher score wins; tie -> lower index wins (matches jax top_k)
__device__ __forceinline__ bool pgt(float as, int ai, float bs, int bi) {
    return (as > bs) || (as == bs && ai < bi);
}

// full bitonic sort across 64 lanes, ascending by priority (validated R6)
__device__ __forceinline__ void bsort(float& s, int& i, int lane) {
#pragma unroll
    for (int k = 2; k <= 64; k <<= 1) {
#pragma unroll
        for (int j = k >> 1; j > 0; j >>= 1) {
            float os = __shfl_xor(s, j, 64);
            int   oi = __shfl_xor(i, j, 64);
            bool lower = (lane & j) == 0;
            bool asc   = (lane & k) == 0;
            bool wmin  = (lower == asc);
            bool takeo = (pgt(s, i, os, oi) == wmin);
            if (takeo) { s = os; i = oi; }
        }
    }
}

// bitonic -> ascending cleanup (6 stages) (validated R6)
__device__ __forceinline__ void bmerge(float& s, int& i, int lane) {
#pragma unroll
    for (int j = 32; j > 0; j >>= 1) {
        float os = __shfl_xor(s, j, 64);
        int   oi = __shfl_xor(i, j, 64);
        bool lower = (lane & j) == 0;
        bool takeo = (pgt(s, i, os, oi) == lower);
        if (takeo) { s = os; i = oi; }
    }
}

// ---- fp32 -> bf16 conversion of x, wq, wkv, wo ----
__global__ __launch_bounds__(256) void convert_bf16(
    const float* __restrict__ x, const float* __restrict__ wq,
    const float* __restrict__ wkv, const float* __restrict__ wo,
    bf16* __restrict__ cx, bf16* __restrict__ cwq,
    bf16* __restrict__ cwkv, bf16* __restrict__ cwo)
{
    const size_t i0 = (size_t)blockIdx.x * 256 + threadIdx.x;
    const size_t stride = (size_t)gridDim.x * 256;
    for (size_t i = i0; i < 2097152; i += stride) cx[i]   = __float2bfloat16(x[i]);
    for (size_t i = i0; i < 1048576; i += stride) cwq[i]  = __float2bfloat16(wq[i]);
    for (size_t i = i0; i < 524288;  i += stride) cwkv[i] = __float2bfloat16(wkv[i]);
    for (size_t i = i0; i < 1048576; i += stride) cwo[i]  = __float2bfloat16(wo[i]);
}

// ---- MFMA GEMM: C[M,N] fp32 = A[M,K](bf16) @ B[K,N](bf16) + bias[N](fp32)
// 64x64 tile, 4 waves, mfma 16x16x32. (R2 code — validated.)
__global__ __launch_bounds__(256) void gemm_bias(
    const bf16* __restrict__ A, const bf16* __restrict__ B,
    const float* __restrict__ bias, float* __restrict__ C,
    int M, int N, int K)
{
    __shared__ short As[64][32];   // (m, k)
    __shared__ short Bt[64][32];   // (n, k)
    const int tid = threadIdx.x;
    const int m0 = blockIdx.y * 64, n0 = blockIdx.x * 64;
    const int w = tid >> 6, lane = tid & 63;
    const int q = lane >> 4, mm = lane & 15;
    f32x4 acc[4];
#pragma unroll
    for (int nb = 0; nb < 4; ++nb) acc[nb] = (f32x4){0.f, 0.f, 0.f, 0.f};
    const int arow = tid >> 2, akc = (tid & 3) * 8;
    const int brow = tid >> 3, bnc = (tid & 7) * 8;
    const short* Ag = (const short*)A;
    const short* Bg = (const short*)B;
    for (int k0 = 0; k0 < K; k0 += 32) {
        __syncthreads();
        short8 av = *(const short8*)(Ag + (size_t)(m0 + arow) * K + k0 + akc);
        *(short8*)(&As[arow][akc]) = av;
        short8 bv = *(const short8*)(Bg + (size_t)(k0 + brow) * N + n0 + bnc);
#pragma unroll
        for (int jj = 0; jj < 8; ++jj) Bt[bnc + jj][brow] = bv[jj];
        __syncthreads();
        short8 af = *(const short8*)(&As[w * 16 + mm][q * 8]);
#pragma unroll
        for (int nb = 0; nb < 4; ++nb) {
            short8 bfr = *(const short8*)(&Bt[nb * 16 + mm][q * 8]);
            acc[nb] = __builtin_amdgcn_mfma_f32_16x16x32_bf16(af, bfr, acc[nb], 0, 0, 0);
        }
    }
#pragma unroll
    for (int nb = 0; nb < 4; ++nb) {
#pragma unroll
        for (int r = 0; r < 4; ++r) {
            int row = m0 + w * 16 + q * 4 + r;
            int col = n0 + nb * 16 + mm;
            C[(size_t)row * N + col] = acc[nb][r] + bias[col];
        }
    }
}

// ---- RMSNorm q and k; emit f16 Q (scale 1/8 folded), f16 K (kvh,t,d), fp32 V ----
__global__ __launch_bounds__(256) void norm_kernel(
    const float* __restrict__ qbuf, const float* __restrict__ kvbuf,
    const float* __restrict__ qn_w, const float* __restrict__ kn_w,
    _Float16* __restrict__ qh, _Float16* __restrict__ kh, float* __restrict__ vbuf)
{
    const int t = blockIdx.x;
    const int tid = threadIdx.x;
#pragma unroll
    for (int it = 0; it < 6; ++it) {
        int idx = it * 256 + tid;
        int chunk = idx >> 6;        // 0..15 q heads, 16..19 k kvh, 20..23 v kvh
        int d = idx & 63;
        float val;
        if (chunk < 16)      val = qbuf[(size_t)t * DMODEL + chunk * 64 + d];
        else if (chunk < 20) val = kvbuf[(size_t)t * 512 + (chunk - 16) * 64 + d];
        else                 val = kvbuf[(size_t)t * 512 + 256 + (chunk - 20) * 64 + d];
        if (chunk < 20) {
            float ss = val * val;
#pragma unroll
            for (int j = 32; j > 0; j >>= 1) ss += __shfl_xor(ss, j, 64);
            float rs = 1.0f / sqrtf(ss * (1.0f / 64.0f) + 1e-8f);
            if (chunk < 16) {
                qh[(size_t)t * DMODEL + chunk * 64 + d] =
                    (_Float16)(val * rs * qn_w[d] * 0.125f);
            } else {
                kh[((size_t)(chunk - 16) * TSEQ + t) * HDIM + d] =
                    (_Float16)(val * rs * kn_w[d]);
            }
        } else {
            vbuf[((size_t)(chunk - 20) * TSEQ + t) * HDIM + d] = val;
        }
    }
}

// ---- fused MFMA scores + exact top-64 + softmax + V gather ----
// block = 1024 threads = 16 waves = one (h, 16-query tile).
// Waves 0-3 compute each 16x64 score chunk via mfma_f32_16x16x32_f16 into a
// double-buffered LDS tile (wave w does key sub-tile jt=w); ALL 16 waves then
// gate+merge their OWN row (wave w = query row w) — one kept-64 per row over
// all chunks, newest-first: identical selection semantics & merge volume to
// the validated one-wave-per-(h,t) baseline, with scores on the matrix pipe.
__global__ __launch_bounds__(1024, 8) void attn_kernel(
    const _Float16* __restrict__ qh, const _Float16* __restrict__ kh,
    const float* __restrict__ vbuf, bf16* __restrict__ ybuf)
{
    __shared__ float Sb[2][16][68];   // double-buffered score tile (2-way banks = free)
    const int tid = threadIdx.x;
    const int w = tid >> 6, lane = tid & 63;
    const int mm = lane & 15, q4 = lane >> 4;
    const int h = blockIdx.x & 15;
    const int t0 = (127 - (blockIdx.x >> 4)) << 4;   // heavy blocks first
    const int kvh = h >> 2;
    const float slope = exp2f(-((float)h) * (8.0f / 15.0f));
    const _Float16* kbase = kh + (size_t)kvh * TSEQ * HDIM;
    const int nch = (t0 + 15) >> 6;

    // Q fragments (f16, 1/8 scale folded); only waves 0-3 need them.
    // A-frag layout: row = lane&15, k = (lane>>4)*8 .. +7
    half8 qf0 = {}, qf1 = {};
    if (w < 4) {
        const _Float16* qp = qh + (size_t)(t0 + mm) * DMODEL + h * HDIM + q4 * 8;
        qf0 = *(const half8*)(qp);        // d 0..31
        qf1 = *(const half8*)(qp + 32);   // d 32..63
    }

    // prologue: compute chunk nch into buffer 0 (wave w handles keys w*16+mm)
    if (w < 4) {
        const int jb = nch << 6;
        const _Float16* kp = kbase + ((size_t)jb + w * 16 + mm) * HDIM + q4 * 8;
        half8 b0 = *(const half8*)(kp);
        half8 b1 = *(const half8*)(kp + 32);
        f32x4 a = __builtin_amdgcn_mfma_f32_16x16x32_f16(
            qf0, b0, (f32x4){0.f, 0.f, 0.f, 0.f}, 0, 0, 0);
        a = __builtin_amdgcn_mfma_f32_16x16x32_f16(qf1, b1, a, 0, 0, 0);
        // C layout: col = lane&15 (key), row = (lane>>4)*4 + reg (query)
#pragma unroll
        for (int rr = 0; rr < 4; ++rr) Sb[0][q4 * 4 + rr][w * 16 + mm] = a[rr];
    }
    __syncthreads();

    float cs = -1e30f; int ci = 0;   // kept-64 for this wave's row (ascending)
    int nb = 0;
    for (int c = nch; c >= 0; --c) {
        const bool doC = (c > 0) && (w < 4);
        // issue next chunk's K loads early (hide L2 latency under merge)
        half8 b0, b1;
        if (doC) {
            const int jb2 = (c - 1) << 6;
            const _Float16* kp = kbase + ((size_t)jb2 + w * 16 + mm) * HDIM + q4 * 8;
            b0 = *(const half8*)(kp);
            b1 = *(const half8*)(kp + 32);
        }
        // merge chunk c from Sb[nb]: wave w owns query row t0+w
        {
            const int jb = c << 6;
            float sr = Sb[nb][w][lane];
            int dist = (t0 + w) - (jb + lane);
            float s = (dist >= 0) ? sr - slope * (float)dist : -1e30f;
            float th = __shfl(cs, 0, 64);     // current 64th-largest
            if (__any(s >= th)) {
                float ns = s; int ni = jb + lane;
                bsort(ns, ni, lane);
                float rsv = __shfl_xor(ns, 63, 64);   // descending view
                int   riv = __shfl_xor(ni, 63, 64);
                if (pgt(rsv, riv, cs, ci)) { cs = rsv; ci = riv; }
                bmerge(cs, ci, lane);                  // restore ascending
            }
        }
        // finish next chunk: MFMA + store into the other buffer
        if (doC) {
            f32x4 a = __builtin_amdgcn_mfma_f32_16x16x32_f16(
                qf0, b0, (f32x4){0.f, 0.f, 0.f, 0.f}, 0, 0, 0);
            a = __builtin_amdgcn_mfma_f32_16x16x32_f16(qf1, b1, a, 0, 0, 0);
#pragma unroll
            for (int rr = 0; rr < 4; ++rr)
                Sb[nb ^ 1][q4 * 4 + rr][w * 16 + mm] = a[rr];
        }
        nb ^= 1;
        __syncthreads();
    }

    // softmax over kept 64 (pads -1e30 -> weight 0); max at lane 63
    float msx = __shfl(cs, 63, 64);
    bool valid = cs > -1e29f;
    float p = valid ? __expf(cs - msx) : 0.f;
    float l = p;
#pragma unroll
    for (int j2 = 32; j2 > 0; j2 >>= 1) l += __shfl_xor(l, j2, 64);
    float wgt = p / l;
    int widx = valid ? ci : 0;
    // V gather via wave broadcast (coalesced: fixed i -> consecutive lanes)
    float acc = 0.f;
    const float* vb = vbuf + (size_t)kvh * TSEQ * HDIM + lane;
#pragma unroll 8
    for (int i = 0; i < 64; ++i) {
        float wv = __shfl(wgt, i, 64);
        int  ix = __shfl(widx, i, 64);
        acc += wv * vb[(size_t)ix * HDIM];
    }
    ybuf[(size_t)(t0 + w) * DMODEL + h * HDIM + lane] = __float2bfloat16(acc);
}

extern "C" void kernel_launch(void* const* d_in, const int* in_sizes, int n_in,
                              void* d_out, int out_size, void* d_ws, size_t ws_size,
                              hipStream_t stream)
{
    // d_in order: x, wq, bq, wkv, bkv, wo, bo, qn_w, kn_w  (all fp32)
    const float* x    = (const float*)d_in[0];
    const float* wq   = (const float*)d_in[1];
    const float* bq   = (const float*)d_in[2];
    const float* wkv  = (const float*)d_in[3];
    const float* bkv  = (const float*)d_in[4];
    const float* wo   = (const float*)d_in[5];
    const float* bo   = (const float*)d_in[6];
    const float* qn_w = (const float*)d_in[7];
    const float* kn_w = (const float*)d_in[8];
    char* ws = (char*)d_ws;
    // ws layout (28 MB):
    // cx bf16 4M @0 (reused as qh f16 4M after kv-gemm) | cwq 2M @4M | cwkv 1M @6M |
    // cwo 2M @7M | qbuf fp32 8M @9M | kvbuf fp32 4M @17M | kh f16 1M @21M |
    // vbuf fp32 2M @22M | ybuf bf16 4M @24M
    bf16*      cx    = (bf16*)(ws);
    bf16*      cwq   = (bf16*)(ws + ((size_t)4  << 20));
    bf16*      cwkv  = (bf16*)(ws + ((size_t)6  << 20));
    bf16*      cwo   = (bf16*)(ws + ((size_t)7  << 20));
    float*     qbuf  = (float*)(ws + ((size_t)9  << 20));
    float*     kvbuf = (float*)(ws + ((size_t)17 << 20));
    _Float16*  qh    = (_Float16*)(ws);                      // overlays dead cx
    _Float16*  kh    = (_Float16*)(ws + ((size_t)21 << 20));
    float*     vbuf  = (float*)(ws + ((size_t)22 << 20));
    bf16*      ybuf  = (bf16*)(ws + ((size_t)24 << 20));
    float*     out   = (float*)d_out;   // fp32 output

    convert_bf16<<<2048, 256, 0, stream>>>(x, wq, wkv, wo, cx, cwq, cwkv, cwo);
    gemm_bias<<<dim3(DMODEL / 64, TSEQ / 64), 256, 0, stream>>>(
        cx, cwq, bq, qbuf, TSEQ, DMODEL, DMODEL);
    gemm_bias<<<dim3(512 / 64, TSEQ / 64), 256, 0, stream>>>(
        cx, cwkv, bkv, kvbuf, TSEQ, 512, DMODEL);
    norm_kernel<<<TSEQ, 256, 0, stream>>>(qbuf, kvbuf, qn_w, kn_w, qh, kh, vbuf);
    attn_kernel<<<NH * (TSEQ / 16), 1024, 0, stream>>>(qh, kh, vbuf, ybuf);
    gemm_bias<<<dim3(DMODEL / 64, TSEQ / 64), 256, 0, stream>>>(
        ybuf, cwo, bo, out, TSEQ, DMODEL, DMODEL);
}

// Round 3
// 318.626 us; speedup vs baseline: 1.6129x; 1.2368x over previous
//
#include <hip/hip_runtime.h>
#include <hip/hip_bf16.h>
#include <stdint.h>

// Problem constants (fixed by reference)
#define TSEQ   2048
#define DMODEL 1024
#define NH     16
#define HDIM   64
#define NKVH   4

typedef __attribute__((ext_vector_type(8))) short short8;
typedef __attribute__((ext_vector_type(8))) _Float16 half8;
typedef __attribute__((ext_vector_type(4))) float f32x4;
typedef __hip_bfloat16 bf16;

// priority comparator: higher score wins; tie -> lower index wins (matches jax top_k)
__device__ __forceinline__ bool pgt(float as, int ai, float bs, int bi) {
    return (as > bs) || (as == bs && ai < bi);
}

// full bitonic sort across 64 lanes, ascending by priority (validated R6)
__device__ __forceinline__ void bsort(float& s, int& i, int lane) {
#pragma unroll
    for (int k = 2; k <= 64; k <<= 1) {
#pragma unroll
        for (int j = k >> 1; j > 0; j >>= 1) {
            float os = __shfl_xor(s, j, 64);
            int   oi = __shfl_xor(i, j, 64);
            bool lower = (lane & j) == 0;
            bool asc   = (lane & k) == 0;
            bool wmin  = (lower == asc);
            bool takeo = (pgt(s, i, os, oi) == wmin);
            if (takeo) { s = os; i = oi; }
        }
    }
}

// bitonic -> ascending cleanup (6 stages) (validated R6)
__device__ __forceinline__ void bmerge(float& s, int& i, int lane) {
#pragma unroll
    for (int j = 32; j > 0; j >>= 1) {
        float os = __shfl_xor(s, j, 64);
        int   oi = __shfl_xor(i, j, 64);
        bool lower = (lane & j) == 0;
        bool takeo = (pgt(s, i, os, oi) == lower);
        if (takeo) { s = os; i = oi; }
    }
}

// ---- fp32 -> bf16 conversion of x, wq, wkv, wo ----
__global__ __launch_bounds__(256) void convert_bf16(
    const float* __restrict__ x, const float* __restrict__ wq,
    const float* __restrict__ wkv, const float* __restrict__ wo,
    bf16* __restrict__ cx, bf16* __restrict__ cwq,
    bf16* __restrict__ cwkv, bf16* __restrict__ cwo)
{
    const size_t i0 = (size_t)blockIdx.x * 256 + threadIdx.x;
    const size_t stride = (size_t)gridDim.x * 256;
    for (size_t i = i0; i < 2097152; i += stride) cx[i]   = __float2bfloat16(x[i]);
    for (size_t i = i0; i < 1048576; i += stride) cwq[i]  = __float2bfloat16(wq[i]);
    for (size_t i = i0; i < 524288;  i += stride) cwkv[i] = __float2bfloat16(wkv[i]);
    for (size_t i = i0; i < 1048576; i += stride) cwo[i]  = __float2bfloat16(wo[i]);
}

// ---- MFMA GEMM: C[M,N] fp32 = A[M,K](bf16) @ B[K,N](bf16) + bias[N](fp32)
// 64x64 tile, 4 waves, mfma 16x16x32. (R2 code — validated.)
__global__ __launch_bounds__(256) void gemm_bias(
    const bf16* __restrict__ A, const bf16* __restrict__ B,
    const float* __restrict__ bias, float* __restrict__ C,
    int M, int N, int K)
{
    __shared__ short As[64][32];   // (m, k)
    __shared__ short Bt[64][32];   // (n, k)
    const int tid = threadIdx.x;
    const int m0 = blockIdx.y * 64, n0 = blockIdx.x * 64;
    const int w = tid >> 6, lane = tid & 63;
    const int q = lane >> 4, mm = lane & 15;
    f32x4 acc[4];
#pragma unroll
    for (int nb = 0; nb < 4; ++nb) acc[nb] = (f32x4){0.f, 0.f, 0.f, 0.f};
    const int arow = tid >> 2, akc = (tid & 3) * 8;
    const int brow = tid >> 3, bnc = (tid & 7) * 8;
    const short* Ag = (const short*)A;
    const short* Bg = (const short*)B;
    for (int k0 = 0; k0 < K; k0 += 32) {
        __syncthreads();
        short8 av = *(const short8*)(Ag + (size_t)(m0 + arow) * K + k0 + akc);
        *(short8*)(&As[arow][akc]) = av;
        short8 bv = *(const short8*)(Bg + (size_t)(k0 + brow) * N + n0 + bnc);
#pragma unroll
        for (int jj = 0; jj < 8; ++jj) Bt[bnc + jj][brow] = bv[jj];
        __syncthreads();
        short8 af = *(const short8*)(&As[w * 16 + mm][q * 8]);
#pragma unroll
        for (int nb = 0; nb < 4; ++nb) {
            short8 bfr = *(const short8*)(&Bt[nb * 16 + mm][q * 8]);
            acc[nb] = __builtin_amdgcn_mfma_f32_16x16x32_bf16(af, bfr, acc[nb], 0, 0, 0);
        }
    }
#pragma unroll
    for (int nb = 0; nb < 4; ++nb) {
#pragma unroll
        for (int r = 0; r < 4; ++r) {
            int row = m0 + w * 16 + q * 4 + r;
            int col = n0 + nb * 16 + mm;
            C[(size_t)row * N + col] = acc[nb][r] + bias[col];
        }
    }
}

// ---- RMSNorm q and k; emit f16 Q (scale 1/8 folded), f16 K (kvh,t,d), fp32 V ----
__global__ __launch_bounds__(256) void norm_kernel(
    const float* __restrict__ qbuf, const float* __restrict__ kvbuf,
    const float* __restrict__ qn_w, const float* __restrict__ kn_w,
    _Float16* __restrict__ qh, _Float16* __restrict__ kh, float* __restrict__ vbuf)
{
    const int t = blockIdx.x;
    const int tid = threadIdx.x;
#pragma unroll
    for (int it = 0; it < 6; ++it) {
        int idx = it * 256 + tid;
        int chunk = idx >> 6;        // 0..15 q heads, 16..19 k kvh, 20..23 v kvh
        int d = idx & 63;
        float val;
        if (chunk < 16)      val = qbuf[(size_t)t * DMODEL + chunk * 64 + d];
        else if (chunk < 20) val = kvbuf[(size_t)t * 512 + (chunk - 16) * 64 + d];
        else                 val = kvbuf[(size_t)t * 512 + 256 + (chunk - 20) * 64 + d];
        if (chunk < 20) {
            float ss = val * val;
#pragma unroll
            for (int j = 32; j > 0; j >>= 1) ss += __shfl_xor(ss, j, 64);
            float rs = 1.0f / sqrtf(ss * (1.0f / 64.0f) + 1e-8f);
            if (chunk < 16) {
                qh[(size_t)t * DMODEL + chunk * 64 + d] =
                    (_Float16)(val * rs * qn_w[d] * 0.125f);
            } else {
                kh[((size_t)(chunk - 16) * TSEQ + t) * HDIM + d] =
                    (_Float16)(val * rs * kn_w[d]);
            }
        } else {
            vbuf[((size_t)(chunk - 20) * TSEQ + t) * HDIM + d] = val;
        }
    }
}

// ---- fused MFMA scores + exact top-64 + softmax + V gather ----
// block = 1024 threads = 16 waves = one (h, 16-query tile).
// Chunks processed in groups of 4: ALL 16 waves produce (wave w -> key
// sub-tile (w&3) of chunk c-(w>>2)) into a double-buffered 4-chunk LDS score
// tile; ONE barrier per group. Each wave then merges its OWN row (wave w =
// query row w). Selection uses per-lane gate (s >= th, th = stale 64th-largest
// => conservative-safe) + ballot compaction into a per-row candidate buffer;
// the validated bsort/bmerge runs only when >=64 candidates accumulate
// (~5 sorts/row instead of ~nch).
__global__ __launch_bounds__(1024, 4) void attn_kernel(
    const _Float16* __restrict__ qh, const _Float16* __restrict__ kh,
    const float* __restrict__ vbuf, bf16* __restrict__ ybuf)
{
    __shared__ float Sg[2][4][16][68];   // [buf][chunk-in-group][qrow][key]
    __shared__ float cbS[16][128];       // per-row candidate scores
    __shared__ int   cbI[16][128];       // per-row candidate indices
    const int tid = threadIdx.x;
    const int w = tid >> 6, lane = tid & 63;
    const int mm = lane & 15, q4 = lane >> 4;
    const int gc = w >> 2, st = w & 3;   // producer role: chunk-in-group, key-subtile
    const int h = blockIdx.x & 15;
    const int t0 = (127 - (blockIdx.x >> 4)) << 4;   // heavy blocks first
    const int kvh = h >> 2;
    const float slope = exp2f(-((float)h) * (8.0f / 15.0f));
    const _Float16* kbase = kh + (size_t)kvh * TSEQ * HDIM;
    const int nch = (t0 + 15) >> 6;

    // Q fragments (f16, 1/8 scale folded). A-frag: row=lane&15, k=(lane>>4)*8..+7
    const _Float16* qp = qh + (size_t)(t0 + mm) * DMODEL + h * HDIM + q4 * 8;
    half8 qf0 = *(const half8*)(qp);        // d 0..31
    half8 qf1 = *(const half8*)(qp + 32);   // d 32..63

    // prologue: produce group base c=nch into buffer 0
    {
        const int cmy = nch - gc;
        if (cmy >= 0) {
            const int jb = cmy << 6;
            const _Float16* kp = kbase + ((size_t)(jb + st * 16 + mm)) * HDIM + q4 * 8;
            half8 b0 = *(const half8*)(kp);
            half8 b1 = *(const half8*)(kp + 32);
            f32x4 a = __builtin_amdgcn_mfma_f32_16x16x32_f16(
                qf0, b0, (f32x4){0.f, 0.f, 0.f, 0.f}, 0, 0, 0);
            a = __builtin_amdgcn_mfma_f32_16x16x32_f16(qf1, b1, a, 0, 0, 0);
            // C layout: col=lane&15 (key), row=(lane>>4)*4+reg (query)
#pragma unroll
            for (int rr = 0; rr < 4; ++rr)
                Sg[0][gc][q4 * 4 + rr][st * 16 + mm] = a[rr];
        }
    }
    __syncthreads();

    float cs = -1e30f; int ci = 0;   // kept-64 for this wave's row (ascending)
    float th = -1e30f;               // 64th-largest so far (stale ok: weaker gate)
    int cnt0 = 0;                    // pending candidates in buffer
    int p = 0;
    for (int c = nch; c >= 0; c -= 4) {
        // issue next group's K loads early (hide L2 latency under merge)
        const int cmy2 = c - 4 - gc;
        half8 b0, b1;
        if (cmy2 >= 0) {
            const int jb2 = cmy2 << 6;
            const _Float16* kp = kbase + ((size_t)(jb2 + st * 16 + mm)) * HDIM + q4 * 8;
            b0 = *(const half8*)(kp);
            b1 = *(const half8*)(kp + 32);
        }
        // merge up to 4 chunks of current group from Sg[p]; wave w = row t0+w
        for (int gi = 0; gi < 4; ++gi) {
            const int cc = c - gi;
            if (cc < 0) break;
            const int jb = cc << 6;
            float sr = Sg[p][gi][w][lane];
            int dist = (t0 + w) - (jb + lane);
            float s = sr - slope * (float)dist;
            bool pass = (dist >= 0) && (s >= th);
            unsigned long long mk = __ballot(pass);
            if (mk) {
                int rank = __popcll(mk & ((1ull << lane) - 1ull));
                if (pass) { cbS[w][cnt0 + rank] = s; cbI[w][cnt0 + rank] = jb + lane; }
                cnt0 += __popcll(mk);
                if (cnt0 >= 64) {
                    float ns = cbS[w][lane];
                    int   ni = cbI[w][lane];
                    bsort(ns, ni, lane);
                    float rsv = __shfl_xor(ns, 63, 64);   // descending view
                    int   riv = __shfl_xor(ni, 63, 64);
                    if (pgt(rsv, riv, cs, ci)) { cs = rsv; ci = riv; }
                    bmerge(cs, ci, lane);                  // restore ascending
                    th = __shfl(cs, 0, 64);
                    int rem = cnt0 - 64;
                    float ms = 0.f; int mi = 0;
                    if (lane < rem) { ms = cbS[w][64 + lane]; mi = cbI[w][64 + lane]; }
                    if (lane < rem) { cbS[w][lane] = ms; cbI[w][lane] = mi; }
                    cnt0 = rem;
                }
            }
        }
        // produce next group into the other buffer
        if (cmy2 >= 0) {
            f32x4 a = __builtin_amdgcn_mfma_f32_16x16x32_f16(
                qf0, b0, (f32x4){0.f, 0.f, 0.f, 0.f}, 0, 0, 0);
            a = __builtin_amdgcn_mfma_f32_16x16x32_f16(qf1, b1, a, 0, 0, 0);
#pragma unroll
            for (int rr = 0; rr < 4; ++rr)
                Sg[p ^ 1][gc][q4 * 4 + rr][st * 16 + mm] = a[rr];
        }
        p ^= 1;
        __syncthreads();
    }
    // flush remaining candidates (pads lose to everything incl. -1e30 kept pads)
    if (cnt0 > 0) {
        float ns = (lane < cnt0) ? cbS[w][lane] : -2e30f;
        int   ni = (lane < cnt0) ? cbI[w][lane] : 0;
        bsort(ns, ni, lane);
        float rsv = __shfl_xor(ns, 63, 64);
        int   riv = __shfl_xor(ni, 63, 64);
        if (pgt(rsv, riv, cs, ci)) { cs = rsv; ci = riv; }
        bmerge(cs, ci, lane);
    }

    // softmax over kept 64 (pads -1e30 -> weight 0); max at lane 63
    float msx = __shfl(cs, 63, 64);
    bool valid = cs > -1e29f;
    float pr = valid ? __expf(cs - msx) : 0.f;
    float l = pr;
#pragma unroll
    for (int j2 = 32; j2 > 0; j2 >>= 1) l += __shfl_xor(l, j2, 64);
    float wgt = pr / l;
    int widx = valid ? ci : 0;
    // V gather via wave broadcast (coalesced: fixed i -> consecutive lanes)
    float acc = 0.f;
    const float* vb = vbuf + (size_t)kvh * TSEQ * HDIM + lane;
#pragma unroll 8
    for (int i = 0; i < 64; ++i) {
        float wv = __shfl(wgt, i, 64);
        int  ix = __shfl(widx, i, 64);
        acc += wv * vb[(size_t)ix * HDIM];
    }
    ybuf[(size_t)(t0 + w) * DMODEL + h * HDIM + lane] = __float2bfloat16(acc);
}

extern "C" void kernel_launch(void* const* d_in, const int* in_sizes, int n_in,
                              void* d_out, int out_size, void* d_ws, size_t ws_size,
                              hipStream_t stream)
{
    // d_in order: x, wq, bq, wkv, bkv, wo, bo, qn_w, kn_w  (all fp32)
    const float* x    = (const float*)d_in[0];
    const float* wq   = (const float*)d_in[1];
    const float* bq   = (const float*)d_in[2];
    const float* wkv  = (const float*)d_in[3];
    const float* bkv  = (const float*)d_in[4];
    const float* wo   = (const float*)d_in[5];
    const float* bo   = (const float*)d_in[6];
    const float* qn_w = (const float*)d_in[7];
    const float* kn_w = (const float*)d_in[8];
    char* ws = (char*)d_ws;
    // ws layout (28 MB):
    // cx bf16 4M @0 (reused as qh f16 4M after kv-gemm) | cwq 2M @4M | cwkv 1M @6M |
    // cwo 2M @7M | qbuf fp32 8M @9M | kvbuf fp32 4M @17M | kh f16 1M @21M |
    // vbuf fp32 2M @22M | ybuf bf16 4M @24M
    bf16*      cx    = (bf16*)(ws);
    bf16*      cwq   = (bf16*)(ws + ((size_t)4  << 20));
    bf16*      cwkv  = (bf16*)(ws + ((size_t)6  << 20));
    bf16*      cwo   = (bf16*)(ws + ((size_t)7  << 20));
    float*     qbuf  = (float*)(ws + ((size_t)9  << 20));
    float*     kvbuf = (float*)(ws + ((size_t)17 << 20));
    _Float16*  qh    = (_Float16*)(ws);                      // overlays dead cx
    _Float16*  kh    = (_Float16*)(ws + ((size_t)21 << 20));
    float*     vbuf  = (float*)(ws + ((size_t)22 << 20));
    bf16*      ybuf  = (bf16*)(ws + ((size_t)24 << 20));
    float*     out   = (float*)d_out;   // fp32 output

    convert_bf16<<<2048, 256, 0, stream>>>(x, wq, wkv, wo, cx, cwq, cwkv, cwo);
    gemm_bias<<<dim3(DMODEL / 64, TSEQ / 64), 256, 0, stream>>>(
        cx, cwq, bq, qbuf, TSEQ, DMODEL, DMODEL);
    gemm_bias<<<dim3(512 / 64, TSEQ / 64), 256, 0, stream>>>(
        cx, cwkv, bkv, kvbuf, TSEQ, 512, DMODEL);
    norm_kernel<<<TSEQ, 256, 0, stream>>>(qbuf, kvbuf, qn_w, kn_w, qh, kh, vbuf);
    attn_kernel<<<NH * (TSEQ / 16), 1024, 0, stream>>>(qh, kh, vbuf, ybuf);
    gemm_bias<<<dim3(DMODEL / 64, TSEQ / 64), 256, 0, stream>>>(
        ybuf, cwo, bo, out, TSEQ, DMODEL, DMODEL);
}

// Round 4
// 277.813 us; speedup vs baseline: 1.8499x; 1.1469x over previous
//
#include <hip/hip_runtime.h>
#include <hip/hip_bf16.h>
#include <stdint.h>

// Problem constants (fixed by reference)
#define TSEQ   2048
#define DMODEL 1024
#define NH     16
#define HDIM   64
#define NKVH   4

typedef __attribute__((ext_vector_type(8))) short short8;
typedef __attribute__((ext_vector_type(8))) _Float16 half8;
typedef __attribute__((ext_vector_type(4))) float f32x4;
typedef __hip_bfloat16 bf16;

// async global->LDS, 16B per lane (linear LDS dest = wave base + lane*16)
__device__ __forceinline__ void gload16(const void* g, void* l) {
    __builtin_amdgcn_global_load_lds(
        (const __attribute__((address_space(1))) uint32_t*)g,
        (__attribute__((address_space(3))) uint32_t*)l, 16, 0, 0);
}

// priority comparator: higher score wins; tie -> lower index wins (matches jax top_k)
__device__ __forceinline__ bool pgt(float as, int ai, float bs, int bi) {
    return (as > bs) || (as == bs && ai < bi);
}

// full bitonic sort across 64 lanes, ascending by priority (validated R6)
__device__ __forceinline__ void bsort(float& s, int& i, int lane) {
#pragma unroll
    for (int k = 2; k <= 64; k <<= 1) {
#pragma unroll
        for (int j = k >> 1; j > 0; j >>= 1) {
            float os = __shfl_xor(s, j, 64);
            int   oi = __shfl_xor(i, j, 64);
            bool lower = (lane & j) == 0;
            bool asc   = (lane & k) == 0;
            bool wmin  = (lower == asc);
            bool takeo = (pgt(s, i, os, oi) == wmin);
            if (takeo) { s = os; i = oi; }
        }
    }
}

// bitonic -> ascending cleanup (6 stages) (validated R6)
__device__ __forceinline__ void bmerge(float& s, int& i, int lane) {
#pragma unroll
    for (int j = 32; j > 0; j >>= 1) {
        float os = __shfl_xor(s, j, 64);
        int   oi = __shfl_xor(i, j, 64);
        bool lower = (lane & j) == 0;
        bool takeo = (pgt(s, i, os, oi) == lower);
        if (takeo) { s = os; i = oi; }
    }
}

// ---- fp32 -> bf16 conversion of x ----
__global__ __launch_bounds__(256) void convert_x(
    const float* __restrict__ x, bf16* __restrict__ cx)
{
    const size_t i0 = (size_t)blockIdx.x * 256 + threadIdx.x;
    const size_t stride = (size_t)gridDim.x * 256;
    for (size_t i = i0; i < 2097152; i += stride) cx[i] = __float2bfloat16(x[i]);
}

// ---- fp32 [R][C] -> bf16 [C][R] tiled transpose-convert (weights, one-shot) ----
__global__ __launch_bounds__(256) void transpose_conv(
    const float* __restrict__ in, bf16* __restrict__ out, int R, int Cc)
{
    __shared__ float tile[32][33];
    const int bx = blockIdx.x * 32;   // col base (n)
    const int by = blockIdx.y * 32;   // row base (k)
    const int tx = threadIdx.x & 31, ty = threadIdx.x >> 5;   // 32 x 8
#pragma unroll
    for (int i = 0; i < 32; i += 8)
        tile[ty + i][tx] = in[(size_t)(by + ty + i) * Cc + bx + tx];
    __syncthreads();
#pragma unroll
    for (int i = 0; i < 32; i += 8)
        out[(size_t)(bx + ty + i) * R + by + tx] = __float2bfloat16(tile[tx][ty + i]);
}

// ---- MFMA GEMM: C[M,N] fp32 = A[M,K](bf16) @ BT[N,K](bf16)^T + bias[N](fp32)
// 64x64 tile, BK=64, 4 waves, mfma 16x16x32, global_load_lds staging with
// T2-style XOR swizzle applied BOTH sides (pre-swizzled global k-slot on the
// staging side, same involution on ds_read addresses — rule #21 pattern).
__global__ __launch_bounds__(256) void gemm_bias(
    const bf16* __restrict__ A, const bf16* __restrict__ BT,
    const float* __restrict__ bias, float* __restrict__ C,
    int M, int N, int K)
{
    __shared__ short As[64][64];   // (m, k-slot-swizzled)  8KB
    __shared__ short Bs[64][64];   // (n, k-slot-swizzled)  8KB
    const int tid = threadIdx.x;
    const int m0 = blockIdx.y * 64, n0 = blockIdx.x * 64;
    const int w = tid >> 6, lane = tid & 63;
    const int q4 = lane >> 4, mm = lane & 15;
    f32x4 acc[4];
#pragma unroll
    for (int nb = 0; nb < 4; ++nb) acc[nb] = (f32x4){0.f, 0.f, 0.f, 0.f};

    // staging: thread covers rows {ar, ar+32}, 16B each; LDS dest linear = tid*16
    const int ar = tid >> 3;                       // 0..31
    const int sslot = (tid & 7) ^ (ar & 7);        // swizzled global k-slot
    const short* Ag = (const short*)A + (size_t)(m0 + ar) * K + sslot * 8;
    const short* Ag2 = (const short*)A + (size_t)(m0 + ar + 32) * K + ((tid & 7) ^ ((ar + 32) & 7)) * 8;
    const short* Bg = (const short*)BT + (size_t)(n0 + ar) * K + sslot * 8;
    const short* Bg2 = (const short*)BT + (size_t)(n0 + ar + 32) * K + ((tid & 7) ^ ((ar + 32) & 7)) * 8;

    // fragment read offsets (shorts), fixed across K-steps; xmask = row&7
    const int xm = mm & 7;
    const short* Asf = (const short*)As;
    const short* Bsf = (const short*)Bs;
    const int aoff0 = (w * 16 + mm) * 64 + ((q4 ^ xm)) * 8;
    const int aoff1 = (w * 16 + mm) * 64 + (((4 + q4) ^ xm)) * 8;
    int boff0[4], boff1[4];
#pragma unroll
    for (int nb = 0; nb < 4; ++nb) {
        boff0[nb] = (nb * 16 + mm) * 64 + ((q4 ^ xm)) * 8;
        boff1[nb] = (nb * 16 + mm) * 64 + (((4 + q4) ^ xm)) * 8;
    }

    for (int k0 = 0; k0 < K; k0 += 64) {
        __syncthreads();
        gload16(Ag + k0, &As[ar][(tid & 7) * 8]);
        gload16(Ag2 + k0, &As[ar + 32][(tid & 7) * 8]);
        gload16(Bg + k0, &Bs[ar][(tid & 7) * 8]);
        gload16(Bg2 + k0, &Bs[ar + 32][(tid & 7) * 8]);
        __syncthreads();   // drains vmcnt (compiler emits it before s_barrier)
        short8 af0 = *(const short8*)(Asf + aoff0);
        short8 af1 = *(const short8*)(Asf + aoff1);
#pragma unroll
        for (int nb = 0; nb < 4; ++nb) {
            short8 b0 = *(const short8*)(Bsf + boff0[nb]);
            short8 b1 = *(const short8*)(Bsf + boff1[nb]);
            acc[nb] = __builtin_amdgcn_mfma_f32_16x16x32_bf16(af0, b0, acc[nb], 0, 0, 0);
            acc[nb] = __builtin_amdgcn_mfma_f32_16x16x32_bf16(af1, b1, acc[nb], 0, 0, 0);
        }
    }
#pragma unroll
    for (int nb = 0; nb < 4; ++nb) {
#pragma unroll
        for (int r = 0; r < 4; ++r) {
            int row = m0 + w * 16 + q4 * 4 + r;
            int col = n0 + nb * 16 + mm;
            C[(size_t)row * N + col] = acc[nb][r] + bias[col];
        }
    }
}

// ---- RMSNorm q and k; emit f16 Q (scale 1/8 folded), f16 K (kvh,t,d), fp32 V ----
__global__ __launch_bounds__(256) void norm_kernel(
    const float* __restrict__ qbuf, const float* __restrict__ kvbuf,
    const float* __restrict__ qn_w, const float* __restrict__ kn_w,
    _Float16* __restrict__ qh, _Float16* __restrict__ kh, float* __restrict__ vbuf)
{
    const int t = blockIdx.x;
    const int tid = threadIdx.x;
#pragma unroll
    for (int it = 0; it < 6; ++it) {
        int idx = it * 256 + tid;
        int chunk = idx >> 6;        // 0..15 q heads, 16..19 k kvh, 20..23 v kvh
        int d = idx & 63;
        float val;
        if (chunk < 16)      val = qbuf[(size_t)t * DMODEL + chunk * 64 + d];
        else if (chunk < 20) val = kvbuf[(size_t)t * 512 + (chunk - 16) * 64 + d];
        else                 val = kvbuf[(size_t)t * 512 + 256 + (chunk - 20) * 64 + d];
        if (chunk < 20) {
            float ss = val * val;
#pragma unroll
            for (int j = 32; j > 0; j >>= 1) ss += __shfl_xor(ss, j, 64);
            float rs = 1.0f / sqrtf(ss * (1.0f / 64.0f) + 1e-8f);
            if (chunk < 16) {
                qh[(size_t)t * DMODEL + chunk * 64 + d] =
                    (_Float16)(val * rs * qn_w[d] * 0.125f);
            } else {
                kh[((size_t)(chunk - 16) * TSEQ + t) * HDIM + d] =
                    (_Float16)(val * rs * kn_w[d]);
            }
        } else {
            vbuf[((size_t)(chunk - 20) * TSEQ + t) * HDIM + d] = val;
        }
    }
}

// ---- fused MFMA scores + exact top-64 + softmax + V gather ----
// (unchanged from R3 — validated)
__global__ __launch_bounds__(1024, 4) void attn_kernel(
    const _Float16* __restrict__ qh, const _Float16* __restrict__ kh,
    const float* __restrict__ vbuf, bf16* __restrict__ ybuf)
{
    __shared__ float Sg[2][4][16][68];   // [buf][chunk-in-group][qrow][key]
    __shared__ float cbS[16][128];       // per-row candidate scores
    __shared__ int   cbI[16][128];       // per-row candidate indices
    const int tid = threadIdx.x;
    const int w = tid >> 6, lane = tid & 63;
    const int mm = lane & 15, q4 = lane >> 4;
    const int gc = w >> 2, st = w & 3;   // producer role: chunk-in-group, key-subtile
    const int h = blockIdx.x & 15;
    const int t0 = (127 - (blockIdx.x >> 4)) << 4;   // heavy blocks first
    const int kvh = h >> 2;
    const float slope = exp2f(-((float)h) * (8.0f / 15.0f));
    const _Float16* kbase = kh + (size_t)kvh * TSEQ * HDIM;
    const int nch = (t0 + 15) >> 6;

    // Q fragments (f16, 1/8 scale folded). A-frag: row=lane&15, k=(lane>>4)*8..+7
    const _Float16* qp = qh + (size_t)(t0 + mm) * DMODEL + h * HDIM + q4 * 8;
    half8 qf0 = *(const half8*)(qp);        // d 0..31
    half8 qf1 = *(const half8*)(qp + 32);   // d 32..63

    // prologue: produce group base c=nch into buffer 0
    {
        const int cmy = nch - gc;
        if (cmy >= 0) {
            const int jb = cmy << 6;
            const _Float16* kp = kbase + ((size_t)(jb + st * 16 + mm)) * HDIM + q4 * 8;
            half8 b0 = *(const half8*)(kp);
            half8 b1 = *(const half8*)(kp + 32);
            f32x4 a = __builtin_amdgcn_mfma_f32_16x16x32_f16(
                qf0, b0, (f32x4){0.f, 0.f, 0.f, 0.f}, 0, 0, 0);
            a = __builtin_amdgcn_mfma_f32_16x16x32_f16(qf1, b1, a, 0, 0, 0);
            // C layout: col=lane&15 (key), row=(lane>>4)*4+reg (query)
#pragma unroll
            for (int rr = 0; rr < 4; ++rr)
                Sg[0][gc][q4 * 4 + rr][st * 16 + mm] = a[rr];
        }
    }
    __syncthreads();

    float cs = -1e30f; int ci = 0;   // kept-64 for this wave's row (ascending)
    float th = -1e30f;               // 64th-largest so far (stale ok: weaker gate)
    int cnt0 = 0;                    // pending candidates in buffer
    int p = 0;
    for (int c = nch; c >= 0; c -= 4) {
        // issue next group's K loads early (hide L2 latency under merge)
        const int cmy2 = c - 4 - gc;
        half8 b0, b1;
        if (cmy2 >= 0) {
            const int jb2 = cmy2 << 6;
            const _Float16* kp = kbase + ((size_t)(jb2 + st * 16 + mm)) * HDIM + q4 * 8;
            b0 = *(const half8*)(kp);
            b1 = *(const half8*)(kp + 32);
        }
        // merge up to 4 chunks of current group from Sg[p]; wave w = row t0+w
        for (int gi = 0; gi < 4; ++gi) {
            const int cc = c - gi;
            if (cc < 0) break;
            const int jb = cc << 6;
            float sr = Sg[p][gi][w][lane];
            int dist = (t0 + w) - (jb + lane);
            float s = sr - slope * (float)dist;
            bool pass = (dist >= 0) && (s >= th);
            unsigned long long mk = __ballot(pass);
            if (mk) {
                int rank = __popcll(mk & ((1ull << lane) - 1ull));
                if (pass) { cbS[w][cnt0 + rank] = s; cbI[w][cnt0 + rank] = jb + lane; }
                cnt0 += __popcll(mk);
                if (cnt0 >= 64) {
                    float ns = cbS[w][lane];
                    int   ni = cbI[w][lane];
                    bsort(ns, ni, lane);
                    float rsv = __shfl_xor(ns, 63, 64);   // descending view
                    int   riv = __shfl_xor(ni, 63, 64);
                    if (pgt(rsv, riv, cs, ci)) { cs = rsv; ci = riv; }
                    bmerge(cs, ci, lane);                  // restore ascending
                    th = __shfl(cs, 0, 64);
                    int rem = cnt0 - 64;
                    float ms = 0.f; int mi = 0;
                    if (lane < rem) { ms = cbS[w][64 + lane]; mi = cbI[w][64 + lane]; }
                    if (lane < rem) { cbS[w][lane] = ms; cbI[w][lane] = mi; }
                    cnt0 = rem;
                }
            }
        }
        // produce next group into the other buffer
        if (cmy2 >= 0) {
            f32x4 a = __builtin_amdgcn_mfma_f32_16x16x32_f16(
                qf0, b0, (f32x4){0.f, 0.f, 0.f, 0.f}, 0, 0, 0);
            a = __builtin_amdgcn_mfma_f32_16x16x32_f16(qf1, b1, a, 0, 0, 0);
#pragma unroll
            for (int rr = 0; rr < 4; ++rr)
                Sg[p ^ 1][gc][q4 * 4 + rr][st * 16 + mm] = a[rr];
        }
        p ^= 1;
        __syncthreads();
    }
    // flush remaining candidates (pads lose to everything incl. -1e30 kept pads)
    if (cnt0 > 0) {
        float ns = (lane < cnt0) ? cbS[w][lane] : -2e30f;
        int   ni = (lane < cnt0) ? cbI[w][lane] : 0;
        bsort(ns, ni, lane);
        float rsv = __shfl_xor(ns, 63, 64);
        int   riv = __shfl_xor(ni, 63, 64);
        if (pgt(rsv, riv, cs, ci)) { cs = rsv; ci = riv; }
        bmerge(cs, ci, lane);
    }

    // softmax over kept 64 (pads -1e30 -> weight 0); max at lane 63
    float msx = __shfl(cs, 63, 64);
    bool valid = cs > -1e29f;
    float pr = valid ? __expf(cs - msx) : 0.f;
    float l = pr;
#pragma unroll
    for (int j2 = 32; j2 > 0; j2 >>= 1) l += __shfl_xor(l, j2, 64);
    float wgt = pr / l;
    int widx = valid ? ci : 0;
    // V gather via wave broadcast (coalesced: fixed i -> consecutive lanes)
    float acc = 0.f;
    const float* vb = vbuf + (size_t)kvh * TSEQ * HDIM + lane;
#pragma unroll 8
    for (int i = 0; i < 64; ++i) {
        float wv = __shfl(wgt, i, 64);
        int  ix = __shfl(widx, i, 64);
        acc += wv * vb[(size_t)ix * HDIM];
    }
    ybuf[(size_t)(t0 + w) * DMODEL + h * HDIM + lane] = __float2bfloat16(acc);
}

extern "C" void kernel_launch(void* const* d_in, const int* in_sizes, int n_in,
                              void* d_out, int out_size, void* d_ws, size_t ws_size,
                              hipStream_t stream)
{
    // d_in order: x, wq, bq, wkv, bkv, wo, bo, qn_w, kn_w  (all fp32)
    const float* x    = (const float*)d_in[0];
    const float* wq   = (const float*)d_in[1];
    const float* bq   = (const float*)d_in[2];
    const float* wkv  = (const float*)d_in[3];
    const float* bkv  = (const float*)d_in[4];
    const float* wo   = (const float*)d_in[5];
    const float* bo   = (const float*)d_in[6];
    const float* qn_w = (const float*)d_in[7];
    const float* kn_w = (const float*)d_in[8];
    char* ws = (char*)d_ws;
    // ws layout (28 MB):
    // cx bf16 4M @0 (reused as qh f16 4M after kv-gemm) | cwqT 2M @4M | cwkvT 1M @6M |
    // cwoT 2M @7M | qbuf fp32 8M @9M | kvbuf fp32 4M @17M | kh f16 1M @21M |
    // vbuf fp32 2M @22M | ybuf bf16 4M @24M
    bf16*      cx    = (bf16*)(ws);
    bf16*      cwqT  = (bf16*)(ws + ((size_t)4  << 20));   // [1024][1024] (n,k)
    bf16*      cwkvT = (bf16*)(ws + ((size_t)6  << 20));   // [512][1024]  (n,k)
    bf16*      cwoT  = (bf16*)(ws + ((size_t)7  << 20));   // [1024][1024] (n,k)
    float*     qbuf  = (float*)(ws + ((size_t)9  << 20));
    float*     kvbuf = (float*)(ws + ((size_t)17 << 20));
    _Float16*  qh    = (_Float16*)(ws);                      // overlays dead cx
    _Float16*  kh    = (_Float16*)(ws + ((size_t)21 << 20));
    float*     vbuf  = (float*)(ws + ((size_t)22 << 20));
    bf16*      ybuf  = (bf16*)(ws + ((size_t)24 << 20));
    float*     out   = (float*)d_out;   // fp32 output

    convert_x<<<1024, 256, 0, stream>>>(x, cx);
    transpose_conv<<<dim3(32, 32), 256, 0, stream>>>(wq, cwqT, 1024, 1024);
    transpose_conv<<<dim3(16, 32), 256, 0, stream>>>(wkv, cwkvT, 1024, 512);
    transpose_conv<<<dim3(32, 32), 256, 0, stream>>>(wo, cwoT, 1024, 1024);
    gemm_bias<<<dim3(DMODEL / 64, TSEQ / 64), 256, 0, stream>>>(
        cx, cwqT, bq, qbuf, TSEQ, DMODEL, DMODEL);
    gemm_bias<<<dim3(512 / 64, TSEQ / 64), 256, 0, stream>>>(
        cx, cwkvT, bkv, kvbuf, TSEQ, 512, DMODEL);
    norm_kernel<<<TSEQ, 256, 0, stream>>>(qbuf, kvbuf, qn_w, kn_w, qh, kh, vbuf);
    attn_kernel<<<NH * (TSEQ / 16), 1024, 0, stream>>>(qh, kh, vbuf, ybuf);
    gemm_bias<<<dim3(DMODEL / 64, TSEQ / 64), 256, 0, stream>>>(
        ybuf, cwoT, bo, out, TSEQ, DMODEL, DMODEL);
}